// Round 8
// baseline (253.451 us; speedup 1.0000x reference)
//
#include <hip/hip_runtime.h>
#include <stdint.h>

#define BB 16384
#define PR2 16896     // 16384 + 8*64 worst-case bucket padding (64-granular)
#define MAXT2 264     // PR2/64 = 8*33

typedef short bf16x8 __attribute__((ext_vector_type(8)));
typedef float f32x4 __attribute__((ext_vector_type(4)));
typedef unsigned short us4v __attribute__((ext_vector_type(4)));

typedef __attribute__((address_space(1))) unsigned short gus_t;
typedef __attribute__((address_space(3))) unsigned short lus_t;

__device__ __forceinline__ unsigned short f2bf(float f) {
    unsigned int u = __float_as_uint(f);
    u += 0x7fffu + ((u >> 16) & 1u);   // RNE
    return (unsigned short)(u >> 16);
}
__device__ __forceinline__ float bf2f(unsigned short h) {
    return __uint_as_float(((unsigned int)h) << 16);
}

__device__ __forceinline__ void gld16(const unsigned short* g, unsigned short* l) {
    __builtin_amdgcn_global_load_lds(
        reinterpret_cast<const gus_t*>(reinterpret_cast<uintptr_t>(g)),
        reinterpret_cast<lus_t*>(reinterpret_cast<uintptr_t>(l)),
        16, 0, 0);
}

// ---------------- weight conversion ----------------
__global__ void cvt_bf16(const float* __restrict__ src, unsigned short* __restrict__ dst, int n4) {
    int stride = gridDim.x * blockDim.x;
    for (int i = blockIdx.x * blockDim.x + threadIdx.x; i < n4; i += stride) {
        f32x4 v = reinterpret_cast<const f32x4*>(src)[i];
        us4v o;
        o[0] = f2bf(v[0]); o[1] = f2bf(v[1]); o[2] = f2bf(v[2]); o[3] = f2bf(v[3]);
        reinterpret_cast<us4v*>(dst)[i] = o;
    }
}

// ---------------- bucketing (64-granular, block-aggregated atomics) ----------------
__global__ void bucket_init(int* perm, int* counts, int* cursors, int* tile_exp) {
    int i = blockIdx.x * blockDim.x + threadIdx.x;
    if (i < PR2) perm[i] = -1;
    if (i < 8) { counts[i] = 0; cursors[i] = 0; }
    if (i < MAXT2) tile_exp[i] = 0;
}

__global__ __launch_bounds__(1024) void bucket_count(const int* __restrict__ y, int* counts) {
    __shared__ int lc[8];
    const int t = threadIdx.x;
    if (t < 8) lc[t] = 0;
    __syncthreads();
    atomicAdd(&lc[y[blockIdx.x * 1024 + t]], 1);
    __syncthreads();
    if (t < 8) atomicAdd(&counts[t], lc[t]);
}

__global__ void bucket_scan(const int* __restrict__ counts, int* starts, int* tile_exp) {
    if (threadIdx.x == 0 && blockIdx.x == 0) {
        int s = 0;
        for (int e = 0; e < 8; ++e) {
            starts[e] = s;
            int nt = (counts[e] + 63) >> 6;
            for (int t = 0; t < nt; ++t) tile_exp[(s >> 6) + t] = e;
            s += nt << 6;
        }
        starts[8] = s;   // total padded rows (multiple of 64)
    }
}

__global__ __launch_bounds__(1024) void bucket_scatter(const int* __restrict__ y,
                                                       const int* __restrict__ starts,
                                                       int* cursors, int* perm) {
    __shared__ int lc[8];
    __shared__ int lbase[8];
    const int t = threadIdx.x;
    if (t < 8) lc[t] = 0;
    __syncthreads();
    const int i = blockIdx.x * 1024 + t;
    const int e = y[i];
    const int r = atomicAdd(&lc[e], 1);
    __syncthreads();
    if (t < 8) lbase[t] = atomicAdd(&cursors[t], lc[t]);
    __syncthreads();
    perm[starts[e] + lbase[e] + r] = i;
}

// ---------------- fused 4-layer MLP: A resident in LDS (64 KB), W streamed to REGISTERS ----
// Key change vs R7: no W-LDS, no DMA staging, no per-step barrier. Each lane loads its
// MFMA B-fragment directly from global (16 B at W + col*512 + st*32 + kg*8) into a
// register triple-buffer (2-step flight). Waves are decoupled within a layer; barriers
// only at the 3 layer boundaries + epilogue. A-LDS layout identical to R7 (verified).
template <int PHASE>
__global__ __launch_bounds__(512, 2) void fused4(
    const float* __restrict__ sf32,
    const unsigned short* __restrict__ srelg,
    const unsigned short* __restrict__ Wb,
    const float* __restrict__ biasb,
    unsigned short* __restrict__ srel_out,
    unsigned short* __restrict__ h_out,
    const unsigned short* __restrict__ h_in,
    float* __restrict__ outf,
    const int* __restrict__ perm,
    const int* __restrict__ tile_exp,
    const int* __restrict__ starts8)
{
    __shared__ __align__(16) unsigned short ls[32768];   // 64 KB: A tile only

    const int bid = blockIdx.x;
    int tile;
    if (PHASE == 0) {
        tile = ((bid & 7) << 5) + (bid >> 3);             // XCD swizzle, 256 = 8*32
    } else {
        tile = (bid & 7) * 33 + (bid >> 3);               // XCD swizzle, 264 = 8*33
        if ((tile << 6) >= starts8[0]) return;
    }

    const unsigned short* Wl;
    const float* bl;
    if (PHASE == 0) { Wl = Wb; bl = biasb; }
    else {
        const int e = tile_exp[tile];
        Wl = Wb + ((size_t)e << 20);
        bl = biasb + (e << 11);
    }

    const int t = threadIdx.x;
    const int w = t >> 6;
    const int lane = t & 63;
    const int lr = lane & 15;
    const int kg = lane >> 4;

    const int asrc_c = (t & 56) | ((t ^ (t >> 6)) & 7);   // inverse-swizzled src chunk
    const int axor = lr & 7;
    int arow_e[4];
#pragma unroll
    for (int m = 0; m < 4; ++m) arow_e[m] = ((m << 4) + lr) << 9;

    // per-lane W fragment base pointers (col = wave-col-block + j*16 + lr)
    const unsigned short* wp[4];
#pragma unroll
    for (int j = 0; j < 4; ++j)
        wp[j] = Wl + (((size_t)((w << 6) + (j << 4) + lr)) << 9) + (kg << 3);

    // biases for all 4 layers
    float bball[16];
#pragma unroll
    for (int l = 0; l < 4; ++l)
#pragma unroll
        for (int j = 0; j < 4; ++j)
            bball[(l << 2) + j] = bl[(l << 9) + (w << 6) + (j << 4) + lr];

    // ---- initial A stage ----
    if (PHASE == 0) {
#pragma unroll
        for (int c8 = 0; c8 < 8; ++c8) {
            const int grow = (tile << 6) + (c8 << 3) + (t >> 6);
            const float* sp = sf32 + (((size_t)grow) << 9) + (asrc_c << 3);
            f32x4 v0 = *reinterpret_cast<const f32x4*>(sp);
            f32x4 v1 = *reinterpret_cast<const f32x4*>(sp + 4);
            bf16x8 o;
#pragma unroll
            for (int q = 0; q < 4; ++q) { o[q] = (short)f2bf(v0[q]); o[q + 4] = (short)f2bf(v1[q]); }
            *reinterpret_cast<bf16x8*>(&ls[(c8 << 12) + (t << 3)]) = o;
        }
    } else {
#pragma unroll
        for (int c8 = 0; c8 < 8; ++c8) {
            int pr = perm[(tile << 6) + (c8 << 3) + (t >> 6)];
            if (pr < 0) pr = 0;
            gld16(srelg + (((size_t)pr) << 9) + (asrc_c << 3), ls + (c8 << 12) + (t << 3));
        }
        asm volatile("s_waitcnt vmcnt(0)" ::: "memory");
    }
    __syncthreads();   // A ready for all waves

    f32x4 acc[4][4];
#pragma unroll
    for (int m = 0; m < 4; ++m)
#pragma unroll
        for (int j = 0; j < 4; ++j)
            acc[m][j] = f32x4{0.f, 0.f, 0.f, 0.f};

    for (int l = 0; l < 4; ++l) {
        const size_t lofs = ((size_t)l) << 18;   // l*262144 elems

        bf16x8 bv[3][4];   // register triple-buffer; all indices static after unroll
#pragma unroll
        for (int j = 0; j < 4; ++j) bv[0][j] = *reinterpret_cast<const bf16x8*>(wp[j] + lofs);
#pragma unroll
        for (int j = 0; j < 4; ++j) bv[1][j] = *reinterpret_cast<const bf16x8*>(wp[j] + lofs + 32);

#pragma unroll
        for (int st = 0; st < 16; ++st) {
            const int cur = st % 3;
            const int nxt = (st + 2) % 3;
            if (st + 2 < 16) {
#pragma unroll
                for (int j = 0; j < 4; ++j)
                    bv[nxt][j] = *reinterpret_cast<const bf16x8*>(wp[j] + lofs + (st + 2) * 32);
            }
            const int sb = (st >> 1) << 6;
            const int klo = ((((st & 1) << 2) | kg) ^ axor) << 3;
            bf16x8 af[4];
#pragma unroll
            for (int m = 0; m < 4; ++m)
                af[m] = *reinterpret_cast<const bf16x8*>(&ls[arow_e[m] + sb + klo]);
#pragma unroll
            for (int m = 0; m < 4; ++m)
#pragma unroll
                for (int j = 0; j < 4; ++j)
                    acc[m][j] = __builtin_amdgcn_mfma_f32_16x16x32_bf16(af[m], bv[cur][j], acc[m][j], 0, 0, 0);
        }

        if (l < 3) {
            __syncthreads();   // all waves done reading A this layer
            const int lbb = l << 2;
#pragma unroll
            for (int m = 0; m < 4; ++m)
#pragma unroll
                for (int j = 0; j < 4; ++j) {
#pragma unroll
                    for (int reg = 0; reg < 4; ++reg) {
                        const int row = (m << 4) + (kg << 2) + reg;
                        const float v = fmaxf(acc[m][j][reg] + bball[lbb + j], 0.f);
                        const int swc = (w << 3) + (((j << 1) + (lr >> 3)) ^ (row & 7));
                        ls[(row << 9) + (swc << 3) + (lr & 7)] = f2bf(v);
                    }
                    acc[m][j] = f32x4{0.f, 0.f, 0.f, 0.f};
                }
            __syncthreads();
        }
    }

    // ---- final epilogue (bball[12..15] = layer-3 bias) ----
    if (PHASE == 0) {
        // pass 1: srel = s - h through LDS -> coalesced bf16 stores
        __syncthreads();
#pragma unroll
        for (int m = 0; m < 4; ++m)
#pragma unroll
            for (int j = 0; j < 4; ++j)
#pragma unroll
                for (int reg = 0; reg < 4; ++reg) {
                    const int row = (m << 4) + (kg << 2) + reg;
                    const int col = (w << 6) + (j << 4) + lr;
                    const float h = fmaxf(acc[m][j][reg] + bball[12 + j], 0.f);
                    const float sv = sf32[(((size_t)((tile << 6) + row)) << 9) + col];
                    const int swc = (w << 3) + (((j << 1) + (lr >> 3)) ^ (row & 7));
                    ls[(row << 9) + (swc << 3) + (lr & 7)] = f2bf(sv - h);
                }
        __syncthreads();
#pragma unroll
        for (int c8 = 0; c8 < 8; ++c8) {
            const int row = (c8 << 3) + (t >> 6);
            const size_t go = (((size_t)((tile << 6) + row)) << 9) + (asrc_c << 3);
            *reinterpret_cast<bf16x8*>(&srel_out[go]) =
                *reinterpret_cast<const bf16x8*>(&ls[(c8 << 12) + (t << 3)]);
        }
        // pass 2: h (acc still live) through LDS -> coalesced bf16 stores
        __syncthreads();
#pragma unroll
        for (int m = 0; m < 4; ++m)
#pragma unroll
            for (int j = 0; j < 4; ++j)
#pragma unroll
                for (int reg = 0; reg < 4; ++reg) {
                    const int row = (m << 4) + (kg << 2) + reg;
                    const float h = fmaxf(acc[m][j][reg] + bball[12 + j], 0.f);
                    const int swc = (w << 3) + (((j << 1) + (lr >> 3)) ^ (row & 7));
                    ls[(row << 9) + (swc << 3) + (lr & 7)] = f2bf(h);
                }
        __syncthreads();
#pragma unroll
        for (int c8 = 0; c8 < 8; ++c8) {
            const int row = (c8 << 3) + (t >> 6);
            const size_t go = (((size_t)((tile << 6) + row)) << 9) + (asrc_c << 3);
            *reinterpret_cast<bf16x8*>(&h_out[go]) =
                *reinterpret_cast<const bf16x8*>(&ls[(c8 << 12) + (t << 3)]);
        }
    } else {
#pragma unroll
        for (int m = 0; m < 4; ++m) {
#pragma unroll
            for (int reg = 0; reg < 4; ++reg) {
                const int row = (m << 4) + (kg << 2) + reg;
                const int pr = perm[(tile << 6) + row];
                if (pr >= 0) {
#pragma unroll
                    for (int j = 0; j < 4; ++j) {
                        const int col = (w << 6) + (j << 4) + lr;
                        const size_t gi = (((size_t)pr) << 9) + col;
                        outf[gi] = acc[m][j][reg] + bball[12 + j] + bf2f(h_in[gi]);
                    }
                }
            }
        }
    }
}

// ---------------- launch ----------------
extern "C" void kernel_launch(void* const* d_in, const int* in_sizes, int n_in,
                              void* d_out, int out_size, void* d_ws, size_t ws_size,
                              hipStream_t stream)
{
    const float* s     = (const float*)d_in[0];
    const int*   y     = (const int*)d_in[1];
    const float* dec_W = (const float*)d_in[2];
    const float* dec_b = (const float*)d_in[3];
    const float* exp_W = (const float*)d_in[4];
    const float* exp_b = (const float*)d_in[5];
    float* out = (float*)d_out;

    unsigned short* decWb = (unsigned short*)d_ws;              // 4*512*512 bf16 (2 MB)
    unsigned short* expWb = decWb + 4 * 512 * 512;              // 32*512*512 bf16 (16 MB)
    unsigned short* srel  = expWb + 8 * 4 * 512 * 512;          // BB*512 bf16 (16 MB)
    unsigned short* hbuf  = srel + (size_t)BB * 512;            // BB*512 bf16 (16 MB)
    int* perm     = (int*)(hbuf + (size_t)BB * 512);            // PR2
    int* counts   = perm + PR2;                                 // 8
    int* cursors  = counts + 8;                                 // 8
    int* starts   = cursors + 8;                                // 9
    int* tile_exp = starts + 9;                                 // MAXT2

    cvt_bf16<<<256, 256, 0, stream>>>(dec_W, decWb, (4 * 512 * 512) / 4);
    cvt_bf16<<<2048, 256, 0, stream>>>(exp_W, expWb, (8 * 4 * 512 * 512) / 4);

    bucket_init<<<(PR2 + 255) / 256, 256, 0, stream>>>(perm, counts, cursors, tile_exp);
    bucket_count<<<BB / 1024, 1024, 0, stream>>>(y, counts);
    bucket_scan<<<1, 64, 0, stream>>>(counts, starts, tile_exp);
    bucket_scatter<<<BB / 1024, 1024, 0, stream>>>(y, starts, cursors, perm);

    fused4<0><<<256, 512, 0, stream>>>(s, nullptr, decWb, dec_b, srel, hbuf,
                                       nullptr, nullptr, nullptr, nullptr, nullptr);
    fused4<1><<<MAXT2, 512, 0, stream>>>(nullptr, srel, expWb, exp_b, nullptr, nullptr,
                                         hbuf, out, perm, tile_exp, starts + 8);
}

// Round 9
// 182.857 us; speedup vs baseline: 1.3861x; 1.3861x over previous
//
#include <hip/hip_runtime.h>
#include <stdint.h>

#define BB 16384
#define PR2 16896     // 16384 + 8*64 worst-case bucket padding (64-granular)
#define MAXT2 264     // PR2/64 = 8*33

typedef short bf16x8 __attribute__((ext_vector_type(8)));
typedef float f32x4 __attribute__((ext_vector_type(4)));
typedef unsigned short us4v __attribute__((ext_vector_type(4)));

typedef __attribute__((address_space(1))) unsigned short gus_t;
typedef __attribute__((address_space(3))) unsigned short lus_t;

__device__ __forceinline__ unsigned short f2bf(float f) {
    unsigned int u = __float_as_uint(f);
    u += 0x7fffu + ((u >> 16) & 1u);   // RNE
    return (unsigned short)(u >> 16);
}
__device__ __forceinline__ float bf2f(unsigned short h) {
    return __uint_as_float(((unsigned int)h) << 16);
}

__device__ __forceinline__ void gld16(const unsigned short* g, unsigned short* l) {
    __builtin_amdgcn_global_load_lds(
        reinterpret_cast<const gus_t*>(reinterpret_cast<uintptr_t>(g)),
        reinterpret_cast<lus_t*>(reinterpret_cast<uintptr_t>(l)),
        16, 0, 0);
}

// ---------------- weight conversion ----------------
__global__ void cvt_bf16(const float* __restrict__ src, unsigned short* __restrict__ dst, int n4) {
    int stride = gridDim.x * blockDim.x;
    for (int i = blockIdx.x * blockDim.x + threadIdx.x; i < n4; i += stride) {
        f32x4 v = reinterpret_cast<const f32x4*>(src)[i];
        us4v o;
        o[0] = f2bf(v[0]); o[1] = f2bf(v[1]); o[2] = f2bf(v[2]); o[3] = f2bf(v[3]);
        reinterpret_cast<us4v*>(dst)[i] = o;
    }
}

// ---------------- bucketing (64-granular, block-aggregated atomics) ----------------
__global__ void bucket_init(int* perm, int* counts, int* cursors, int* tile_exp) {
    int i = blockIdx.x * blockDim.x + threadIdx.x;
    if (i < PR2) perm[i] = -1;
    if (i < 8) { counts[i] = 0; cursors[i] = 0; }
    if (i < MAXT2) tile_exp[i] = 0;
}

__global__ __launch_bounds__(1024) void bucket_count(const int* __restrict__ y, int* counts) {
    __shared__ int lc[8];
    const int t = threadIdx.x;
    if (t < 8) lc[t] = 0;
    __syncthreads();
    atomicAdd(&lc[y[blockIdx.x * 1024 + t]], 1);
    __syncthreads();
    if (t < 8) atomicAdd(&counts[t], lc[t]);
}

__global__ void bucket_scan(const int* __restrict__ counts, int* starts, int* tile_exp) {
    if (threadIdx.x == 0 && blockIdx.x == 0) {
        int s = 0;
        for (int e = 0; e < 8; ++e) {
            starts[e] = s;
            int nt = (counts[e] + 63) >> 6;
            for (int t = 0; t < nt; ++t) tile_exp[(s >> 6) + t] = e;
            s += nt << 6;
        }
        starts[8] = s;   // total padded rows (multiple of 64)
    }
}

__global__ __launch_bounds__(1024) void bucket_scatter(const int* __restrict__ y,
                                                       const int* __restrict__ starts,
                                                       int* cursors, int* perm) {
    __shared__ int lc[8];
    __shared__ int lbase[8];
    const int t = threadIdx.x;
    if (t < 8) lc[t] = 0;
    __syncthreads();
    const int i = blockIdx.x * 1024 + t;
    const int e = y[i];
    const int r = atomicAdd(&lc[e], 1);
    __syncthreads();
    if (t < 8) lbase[t] = atomicAdd(&cursors[t], lc[t]);
    __syncthreads();
    perm[starts[e] + lbase[e] + r] = i;
}

// ---------------- fused 4-layer MLP: wave-decoupled K-staggered DMA pipeline ----------------
// LDS (exactly 160 KiB): A = ls[0..32768) elems (64 KB, layout as R5-R7, verified);
// W = 8 waves x 3 private buffers x 2048 elems at ls+32768+w*6144+buf*2048.
// Each wave stages ONLY its own 64-col x 32-K slice per step (4 x gld16, line-contiguous
// source: 16 full 64B lines per instr), double...triple-buffered, self-paced via its own
// vmcnt — NO barriers within a layer. Wave (tile,w) starts at K-step offset
// ((tile*3+w)&15): accumulation commutes; decorrelates L2 reads across 2048 waves.
// W buffer layout: col-major 64B (slot(c,kg) = c*64B + kg*16B) -> conflict-free b128
// reads (m97 structure) AND line-contiguous DMA source.
#define STAGE(x_) do {                                                        \
    const unsigned short* wp_ = Wl + (((size_t)((x_) >> 4)) << 18)            \
        + ((size_t)((((x_) & 15) + off) & 15) << 5) + wsrc_off;               \
    unsigned short* ld_ = wdst0 + (((x_) % 3) << 11);                         \
    gld16(wp_,         ld_);                                                  \
    gld16(wp_ +  8192, ld_ +  512);                                           \
    gld16(wp_ + 16384, ld_ + 1024);                                           \
    gld16(wp_ + 24576, ld_ + 1536);                                           \
} while (0)

template <int PHASE>
__global__ __launch_bounds__(512) void fused4(
    const float* __restrict__ sf32,
    const unsigned short* __restrict__ srelg,
    const unsigned short* __restrict__ Wb,
    const float* __restrict__ biasb,
    unsigned short* __restrict__ srel_out,
    unsigned short* __restrict__ h_out,
    const unsigned short* __restrict__ h_in,
    float* __restrict__ outf,
    const int* __restrict__ perm,
    const int* __restrict__ tile_exp,
    const int* __restrict__ starts8)
{
    __shared__ __align__(16) unsigned short ls[81920];   // 160 KiB exact

    const int bid = blockIdx.x;
    int tile;
    if (PHASE == 0) {
        tile = ((bid & 7) << 5) + (bid >> 3);             // XCD swizzle, 256 = 8*32
    } else {
        tile = (bid & 7) * 33 + (bid >> 3);               // XCD swizzle, 264 = 8*33
        if ((tile << 6) >= starts8[0]) return;
    }

    const unsigned short* Wl;
    const float* bl;
    if (PHASE == 0) { Wl = Wb; bl = biasb; }
    else {
        const int e = tile_exp[tile];
        Wl = Wb + ((size_t)e << 20);
        bl = biasb + (e << 11);
    }

    const int t = threadIdx.x;
    const int w = t >> 6;
    const int lane = t & 63;
    const int lr = lane & 15;
    const int kg = lane >> 4;
    const int off = ((tile * 3) + w) & 15;                // per-wave K-stagger

    const int asrc_c = (t & 56) | ((t ^ (t >> 6)) & 7);   // A inverse-swizzled src chunk
    const int axor = lr & 7;
    int arow_e[4];
#pragma unroll
    for (int m = 0; m < 4; ++m) arow_e[m] = ((m << 4) + lr) << 9;

    // W staging: instr q covers cols wcb+q*16+(lane>>2), k-chunk (lane&3)
    const int wcb = w << 6;
    const size_t wsrc_off = (((size_t)(wcb + (lane >> 2))) << 9) + ((lane & 3) << 3);
    unsigned short* const wdst0 = ls + 32768 + w * 6144 + (lane << 3);
    // W read: frag j at wrd0 + buf*2048 + j*512
    const int wrd0 = 32768 + w * 6144 + (lr << 5) + (kg << 3);

    // ---- biases for all 4 layers, fenced before any gld16 ----
    float bball[16];
#pragma unroll
    for (int l = 0; l < 4; ++l)
#pragma unroll
        for (int j = 0; j < 4; ++j)
            bball[(l << 2) + j] = bl[(l << 9) + (w << 6) + (j << 4) + lr];
    asm volatile("s_waitcnt vmcnt(0)" ::: "memory");

    // ---- initial A stage ----
    if (PHASE == 0) {
#pragma unroll
        for (int c8 = 0; c8 < 8; ++c8) {
            const int grow = (tile << 6) + (c8 << 3) + w;
            const float* sp = sf32 + (((size_t)grow) << 9) + (asrc_c << 3);
            f32x4 v0 = *reinterpret_cast<const f32x4*>(sp);
            f32x4 v1 = *reinterpret_cast<const f32x4*>(sp + 4);
            bf16x8 o;
#pragma unroll
            for (int q = 0; q < 4; ++q) { o[q] = (short)f2bf(v0[q]); o[q + 4] = (short)f2bf(v1[q]); }
            *reinterpret_cast<bf16x8*>(&ls[(c8 << 12) + (t << 3)]) = o;
        }
        asm volatile("s_waitcnt lgkmcnt(0)" ::: "memory");
    } else {
#pragma unroll
        for (int c8 = 0; c8 < 8; ++c8) {
            int pr = perm[(tile << 6) + (c8 << 3) + w];
            if (pr < 0) pr = 0;
            gld16(srelg + (((size_t)pr) << 9) + (asrc_c << 3), ls + (c8 << 12) + (t << 3));
        }
        asm volatile("s_waitcnt vmcnt(0)" ::: "memory");
    }
    STAGE(0);
    STAGE(1);
    __builtin_amdgcn_s_barrier();        // A visible to all waves; stages in flight

    f32x4 acc[4][4];
#pragma unroll
    for (int m = 0; m < 4; ++m)
#pragma unroll
        for (int j = 0; j < 4; ++j)
            acc[m][j] = f32x4{0.f, 0.f, 0.f, 0.f};

    // ---- main loop: 64 K-steps, wave-private pipeline, barriers only at layer ends ----
    for (int s = 0; s < 64; ++s) {
        if (s < 63) asm volatile("s_waitcnt vmcnt(4)" ::: "memory");
        else        asm volatile("s_waitcnt vmcnt(0)" ::: "memory");
        if (s + 2 < 64) STAGE(s + 2);    // refill buf read at s-1 (own program order)

        const int st = ((s & 15) + off) & 15;
        const int sb = (st >> 1) << 6;
        const int klo = ((((st & 1) << 2) | kg) ^ axor) << 3;
        const int wb = (s % 3) << 11;
        bf16x8 af[4], bv[4];
#pragma unroll
        for (int m = 0; m < 4; ++m)
            af[m] = *reinterpret_cast<const bf16x8*>(&ls[arow_e[m] + sb + klo]);
#pragma unroll
        for (int j = 0; j < 4; ++j)
            bv[j] = *reinterpret_cast<const bf16x8*>(&ls[wrd0 + wb + (j << 9)]);
        __builtin_amdgcn_s_setprio(1);
#pragma unroll
        for (int m = 0; m < 4; ++m)
#pragma unroll
            for (int j = 0; j < 4; ++j)
                acc[m][j] = __builtin_amdgcn_mfma_f32_16x16x32_bf16(af[m], bv[j], acc[m][j], 0, 0, 0);
        __builtin_amdgcn_s_setprio(0);

        if ((s & 15) == 15 && s < 63) {
            // layer boundary: program order guarantees each wave's A-reads retired
            __builtin_amdgcn_s_barrier();
            asm volatile("" ::: "memory");
            const int lbb = (s >> 4) << 2;
#pragma unroll
            for (int m = 0; m < 4; ++m)
#pragma unroll
                for (int j = 0; j < 4; ++j) {
#pragma unroll
                    for (int reg = 0; reg < 4; ++reg) {
                        const int row = (m << 4) + (kg << 2) + reg;
                        const float v = fmaxf(acc[m][j][reg] + bball[lbb + j], 0.f);
                        const int swc = (w << 3) + (((j << 1) + (lr >> 3)) ^ (row & 7));
                        ls[(row << 9) + (swc << 3) + (lr & 7)] = f2bf(v);
                    }
                    acc[m][j] = f32x4{0.f, 0.f, 0.f, 0.f};
                }
            asm volatile("s_waitcnt lgkmcnt(0)" ::: "memory");
            __builtin_amdgcn_s_barrier();
            asm volatile("" ::: "memory");
        }
    }

    // ---- final epilogue (bball[12..15] = layer-3 bias) ----
    if (PHASE == 0) {
        __syncthreads();
#pragma unroll
        for (int m = 0; m < 4; ++m)
#pragma unroll
            for (int j = 0; j < 4; ++j)
#pragma unroll
                for (int reg = 0; reg < 4; ++reg) {
                    const int row = (m << 4) + (kg << 2) + reg;
                    const int col = (w << 6) + (j << 4) + lr;
                    const float h = fmaxf(acc[m][j][reg] + bball[12 + j], 0.f);
                    const float sv = sf32[(((size_t)((tile << 6) + row)) << 9) + col];
                    const int swc = (w << 3) + (((j << 1) + (lr >> 3)) ^ (row & 7));
                    const int idx = (row << 9) + (swc << 3) + (lr & 7);
                    ls[idx] = f2bf(sv - h);             // srel in A area
                    ls[32768 + idx] = f2bf(h);          // h in W area
                }
        __syncthreads();
#pragma unroll
        for (int c8 = 0; c8 < 8; ++c8) {
            const int row = (c8 << 3) + w;
            const size_t go = (((size_t)((tile << 6) + row)) << 9) + (asrc_c << 3);
            bf16x8 va = *reinterpret_cast<const bf16x8*>(&ls[(c8 << 12) + (t << 3)]);
            bf16x8 vh = *reinterpret_cast<const bf16x8*>(&ls[32768 + (c8 << 12) + (t << 3)]);
            *reinterpret_cast<bf16x8*>(&srel_out[go]) = va;
            *reinterpret_cast<bf16x8*>(&h_out[go]) = vh;
        }
    } else {
#pragma unroll
        for (int m = 0; m < 4; ++m) {
#pragma unroll
            for (int reg = 0; reg < 4; ++reg) {
                const int row = (m << 4) + (kg << 2) + reg;
                const int pr = perm[(tile << 6) + row];
                if (pr >= 0) {
#pragma unroll
                    for (int j = 0; j < 4; ++j) {
                        const int col = (w << 6) + (j << 4) + lr;
                        const size_t gi = (((size_t)pr) << 9) + col;
                        outf[gi] = acc[m][reg >> 2 == 0 ? j : j][reg] + bball[12 + j] + bf2f(h_in[gi]);
                    }
                }
            }
        }
    }
}

// ---------------- launch ----------------
extern "C" void kernel_launch(void* const* d_in, const int* in_sizes, int n_in,
                              void* d_out, int out_size, void* d_ws, size_t ws_size,
                              hipStream_t stream)
{
    const float* s     = (const float*)d_in[0];
    const int*   y     = (const int*)d_in[1];
    const float* dec_W = (const float*)d_in[2];
    const float* dec_b = (const float*)d_in[3];
    const float* exp_W = (const float*)d_in[4];
    const float* exp_b = (const float*)d_in[5];
    float* out = (float*)d_out;

    unsigned short* decWb = (unsigned short*)d_ws;              // 4*512*512 bf16 (2 MB)
    unsigned short* expWb = decWb + 4 * 512 * 512;              // 32*512*512 bf16 (16 MB)
    unsigned short* srel  = expWb + 8 * 4 * 512 * 512;          // BB*512 bf16 (16 MB)
    unsigned short* hbuf  = srel + (size_t)BB * 512;            // BB*512 bf16 (16 MB)
    int* perm     = (int*)(hbuf + (size_t)BB * 512);            // PR2
    int* counts   = perm + PR2;                                 // 8
    int* cursors  = counts + 8;                                 // 8
    int* starts   = cursors + 8;                                // 9
    int* tile_exp = starts + 9;                                 // MAXT2

    cvt_bf16<<<256, 256, 0, stream>>>(dec_W, decWb, (4 * 512 * 512) / 4);
    cvt_bf16<<<2048, 256, 0, stream>>>(exp_W, expWb, (8 * 4 * 512 * 512) / 4);

    bucket_init<<<(PR2 + 255) / 256, 256, 0, stream>>>(perm, counts, cursors, tile_exp);
    bucket_count<<<BB / 1024, 1024, 0, stream>>>(y, counts);
    bucket_scan<<<1, 64, 0, stream>>>(counts, starts, tile_exp);
    bucket_scatter<<<BB / 1024, 1024, 0, stream>>>(y, starts, cursors, perm);

    fused4<0><<<256, 512, 0, stream>>>(s, nullptr, decWb, dec_b, srel, hbuf,
                                       nullptr, nullptr, nullptr, nullptr, nullptr);
    fused4<1><<<MAXT2, 512, 0, stream>>>(nullptr, srel, expWb, exp_b, nullptr, nullptr,
                                         hbuf, out, perm, tile_exp, starts + 8);
}

// Round 10
// 181.373 us; speedup vs baseline: 1.3974x; 1.0082x over previous
//
#include <hip/hip_runtime.h>
#include <stdint.h>

#define BB 16384
#define PR2 16896     // 16384 + 8*64 worst-case bucket padding (64-granular)
#define MAXT2 264     // PR2/64 = 8*33

typedef short bf16x8 __attribute__((ext_vector_type(8)));
typedef float f32x4 __attribute__((ext_vector_type(4)));
typedef unsigned short us4v __attribute__((ext_vector_type(4)));

typedef __attribute__((address_space(1))) unsigned short gus_t;
typedef __attribute__((address_space(3))) unsigned short lus_t;

__device__ __forceinline__ unsigned short f2bf(float f) {
    unsigned int u = __float_as_uint(f);
    u += 0x7fffu + ((u >> 16) & 1u);   // RNE
    return (unsigned short)(u >> 16);
}
__device__ __forceinline__ float bf2f(unsigned short h) {
    return __uint_as_float(((unsigned int)h) << 16);
}

__device__ __forceinline__ void gld16(const unsigned short* g, unsigned short* l) {
    __builtin_amdgcn_global_load_lds(
        reinterpret_cast<const gus_t*>(reinterpret_cast<uintptr_t>(g)),
        reinterpret_cast<lus_t*>(reinterpret_cast<uintptr_t>(l)),
        16, 0, 0);
}

// ---------------- weight conversion ----------------
__global__ void cvt_bf16(const float* __restrict__ src, unsigned short* __restrict__ dst, int n4) {
    int stride = gridDim.x * blockDim.x;
    for (int i = blockIdx.x * blockDim.x + threadIdx.x; i < n4; i += stride) {
        f32x4 v = reinterpret_cast<const f32x4*>(src)[i];
        us4v o;
        o[0] = f2bf(v[0]); o[1] = f2bf(v[1]); o[2] = f2bf(v[2]); o[3] = f2bf(v[3]);
        reinterpret_cast<us4v*>(dst)[i] = o;
    }
}

// ---------------- bucketing (64-granular, block-aggregated atomics) ----------------
__global__ void bucket_init(int* perm, int* counts, int* cursors, int* tile_exp) {
    int i = blockIdx.x * blockDim.x + threadIdx.x;
    if (i < PR2) perm[i] = -1;
    if (i < 8) { counts[i] = 0; cursors[i] = 0; }
    if (i < MAXT2) tile_exp[i] = 0;
}

__global__ __launch_bounds__(1024) void bucket_count(const int* __restrict__ y, int* counts) {
    __shared__ int lc[8];
    const int t = threadIdx.x;
    if (t < 8) lc[t] = 0;
    __syncthreads();
    atomicAdd(&lc[y[blockIdx.x * 1024 + t]], 1);
    __syncthreads();
    if (t < 8) atomicAdd(&counts[t], lc[t]);
}

__global__ void bucket_scan(const int* __restrict__ counts, int* starts, int* tile_exp) {
    if (threadIdx.x == 0 && blockIdx.x == 0) {
        int s = 0;
        for (int e = 0; e < 8; ++e) {
            starts[e] = s;
            int nt = (counts[e] + 63) >> 6;
            for (int t = 0; t < nt; ++t) tile_exp[(s >> 6) + t] = e;
            s += nt << 6;
        }
        starts[8] = s;   // total padded rows (multiple of 64)
    }
}

__global__ __launch_bounds__(1024) void bucket_scatter(const int* __restrict__ y,
                                                       const int* __restrict__ starts,
                                                       int* cursors, int* perm) {
    __shared__ int lc[8];
    __shared__ int lbase[8];
    const int t = threadIdx.x;
    if (t < 8) lc[t] = 0;
    __syncthreads();
    const int i = blockIdx.x * 1024 + t;
    const int e = y[i];
    const int r = atomicAdd(&lc[e], 1);
    __syncthreads();
    if (t < 8) lbase[t] = atomicAdd(&cursors[t], lc[t]);
    __syncthreads();
    perm[starts[e] + lbase[e] + r] = i;
}

// ---------------- fused 4-layer MLP, register-pipelined (m201 phase idiom) ----------------
// LDS 160 KiB: A = ls[0..32768) elems (layout as R5-R9, verified); W = 8 waves x 3
// private bufs x 2048 elems at 32768 + w*6144 + b*2048.
// W buffer layout [64 col][4 slot][16B], slot=(kg+(col>>1))&3: conflict-free b128 reads
// (each bank touched exactly 8x per wave read) AND coalesced DMA source (4 k-chunks of
// one col = one 64B line; 16 lines per gld16 instr).
// Pipeline per iter s (frags_s already in regs): STAGE(s+2) -> vmcnt(4) [stage s+1 done]
// -> ds_read frags_{s+1} into alternate reg set -> MFMA on frags_s (NO lgkm dependency).
// 2x unrolled for static register rotation. A-prefetch deferred at layer boundaries.
template <int PHASE>
__global__ __launch_bounds__(512) void fused4(
    const float* __restrict__ sf32,
    const unsigned short* __restrict__ srelg,
    const unsigned short* __restrict__ Wb,
    const float* __restrict__ biasb,
    unsigned short* __restrict__ srel_out,
    unsigned short* __restrict__ h_out,
    const unsigned short* __restrict__ h_in,
    float* __restrict__ outf,
    const int* __restrict__ perm,
    const int* __restrict__ tile_exp,
    const int* __restrict__ starts8)
{
    __shared__ __align__(16) unsigned short ls[81920];   // 160 KiB exact

    const int bid = blockIdx.x;
    int tile;
    if (PHASE == 0) {
        tile = ((bid & 7) << 5) + (bid >> 3);             // XCD swizzle, 256 = 8*32
    } else {
        tile = (bid & 7) * 33 + (bid >> 3);               // XCD swizzle, 264 = 8*33
        if ((tile << 6) >= starts8[0]) return;
    }

    const unsigned short* Wl;
    const float* bl;
    if (PHASE == 0) { Wl = Wb; bl = biasb; }
    else {
        const int e = tile_exp[tile];
        Wl = Wb + ((size_t)e << 20);
        bl = biasb + (e << 11);
    }

    const int t = threadIdx.x;
    const int w = t >> 6;
    const int lane = t & 63;
    const int lr = lane & 15;
    const int kg = lane >> 4;
    const int off = ((tile * 3) + w) & 15;                // per-wave K-stagger

    const int asrc_c = (t & 56) | ((t ^ (t >> 6)) & 7);   // A inverse-swizzled src chunk
    const int axor = lr & 7;
    int arow_e[4];
#pragma unroll
    for (int m = 0; m < 4; ++m) arow_e[m] = ((m << 4) + lr) << 9;

    // W stage source constants: instr q, lane l -> col c=q*16+(l>>2), slot=l&3,
    // kg = (slot - (c>>1))&3; src elem offset = (wcb+c)*512 + kg*8
    const int wcb = w << 6;
    int colterm[4];
#pragma unroll
    for (int q = 0; q < 4; ++q) {
        const int cq = (q << 4) + (lane >> 2);
        const int kgq = ((lane & 3) - (cq >> 1)) & 3;
        colterm[q] = ((wcb + cq) << 9) + (kgq << 3);
    }
    const int wavebase = 32768 + w * 6144;                // elems
    unsigned short* const wdst = ls + wavebase + (lane << 3);
    // W read base: frag j at wrd0e + j*512 (+ buf*2048)
    const int wrd0e = (lr << 5) + (((kg + (lr >> 1)) & 3) << 3);

#define STAGE(x_, b_) do {                                               \
    const unsigned short* wp_ = Wl + (((size_t)((x_) >> 4)) << 18)       \
        + (((((x_) & 15) + off) & 15) << 5);                             \
    unsigned short* ld_ = wdst + ((b_) << 11);                           \
    gld16(wp_ + colterm[0], ld_);                                        \
    gld16(wp_ + colterm[1], ld_ +  512);                                 \
    gld16(wp_ + colterm[2], ld_ + 1024);                                 \
    gld16(wp_ + colterm[3], ld_ + 1536);                                 \
} while (0)

#define READW(dst_, b_) do {                                             \
    const unsigned short* lw_ = ls + wavebase + ((b_) << 11) + wrd0e;    \
    dst_[0] = *reinterpret_cast<const bf16x8*>(lw_);                     \
    dst_[1] = *reinterpret_cast<const bf16x8*>(lw_ +  512);              \
    dst_[2] = *reinterpret_cast<const bf16x8*>(lw_ + 1024);              \
    dst_[3] = *reinterpret_cast<const bf16x8*>(lw_ + 1536);              \
} while (0)

#define READA(dst_, s1_) do {                                            \
    const int st_ = (((s1_) & 15) + off) & 15;                           \
    const int sb_ = (st_ >> 1) << 6;                                     \
    const int klo_ = ((((st_ & 1) << 2) | kg) ^ axor) << 3;              \
    dst_[0] = *reinterpret_cast<const bf16x8*>(&ls[arow_e[0] + sb_ + klo_]); \
    dst_[1] = *reinterpret_cast<const bf16x8*>(&ls[arow_e[1] + sb_ + klo_]); \
    dst_[2] = *reinterpret_cast<const bf16x8*>(&ls[arow_e[2] + sb_ + klo_]); \
    dst_[3] = *reinterpret_cast<const bf16x8*>(&ls[arow_e[3] + sb_ + klo_]); \
} while (0)

    // ---- biases for all 4 layers, fenced before any gld16 ----
    float bball[16];
#pragma unroll
    for (int l = 0; l < 4; ++l)
#pragma unroll
        for (int j = 0; j < 4; ++j)
            bball[(l << 2) + j] = bl[(l << 9) + (w << 6) + (j << 4) + lr];
    asm volatile("s_waitcnt vmcnt(0)" ::: "memory");

    // ---- initial A stage + W stage 0,1 + frag prologue ----
    if (PHASE == 0) {
#pragma unroll
        for (int c8 = 0; c8 < 8; ++c8) {
            const int grow = (tile << 6) + (c8 << 3) + w;
            const float* sp = sf32 + (((size_t)grow) << 9) + (asrc_c << 3);
            f32x4 v0 = *reinterpret_cast<const f32x4*>(sp);
            f32x4 v1 = *reinterpret_cast<const f32x4*>(sp + 4);
            bf16x8 o;
#pragma unroll
            for (int q = 0; q < 4; ++q) { o[q] = (short)f2bf(v0[q]); o[q + 4] = (short)f2bf(v1[q]); }
            *reinterpret_cast<bf16x8*>(&ls[(c8 << 12) + (t << 3)]) = o;
        }
        STAGE(0, 0);
        STAGE(1, 1);
        asm volatile("s_waitcnt lgkmcnt(0)" ::: "memory");   // my A-writes done
        __builtin_amdgcn_s_barrier();                        // A visible to all
        asm volatile("s_waitcnt vmcnt(4)" ::: "memory");     // stage 0 complete
    } else {
#pragma unroll
        for (int c8 = 0; c8 < 8; ++c8) {
            int pr = perm[(tile << 6) + (c8 << 3) + w];
            if (pr < 0) pr = 0;
            gld16(srelg + (((size_t)pr) << 9) + (asrc_c << 3), ls + (c8 << 12) + (t << 3));
        }
        STAGE(0, 0);
        STAGE(1, 1);
        asm volatile("s_waitcnt vmcnt(8)" ::: "memory");     // A DMA complete
        __builtin_amdgcn_s_barrier();                        // A visible to all
        asm volatile("s_waitcnt vmcnt(4)" ::: "memory");     // stage 0 complete
    }

    f32x4 acc[4][4];
#pragma unroll
    for (int m = 0; m < 4; ++m)
#pragma unroll
        for (int j = 0; j < 4; ++j)
            acc[m][j] = f32x4{0.f, 0.f, 0.f, 0.f};

    bf16x8 afA[4], bvA[4], afB[4], bvB[4];
    READA(afA, 0);
    READW(bvA, 0);

#define ITER(s_, afC, bvC, afN, bvN) do {                                          \
    if ((s_) + 2 < 64) STAGE((s_) + 2, b2);                                        \
    if ((s_) < 62) asm volatile("s_waitcnt vmcnt(4)" ::: "memory");                \
    else           asm volatile("s_waitcnt vmcnt(0)" ::: "memory");                \
    const bool bnd_ = ((s_) & 15) == 15;                                           \
    if ((s_) < 63) {                                                               \
        READW(bvN, b1);                                                            \
        if (!bnd_) READA(afN, (s_) + 1);                                           \
    }                                                                              \
    __builtin_amdgcn_s_setprio(1);                                                 \
    _Pragma("unroll")                                                              \
    for (int m = 0; m < 4; ++m)                                                    \
        _Pragma("unroll")                                                          \
        for (int j = 0; j < 4; ++j)                                                \
            acc[m][j] = __builtin_amdgcn_mfma_f32_16x16x32_bf16(afC[m], bvC[j], acc[m][j], 0, 0, 0); \
    __builtin_amdgcn_s_setprio(0);                                                 \
    if (bnd_ && (s_) < 63) {                                                       \
        __builtin_amdgcn_s_barrier();                                              \
        const int lbb_ = ((s_) >> 4) << 2;                                         \
        _Pragma("unroll")                                                          \
        for (int m = 0; m < 4; ++m)                                                \
            _Pragma("unroll")                                                      \
            for (int j = 0; j < 4; ++j) {                                          \
                _Pragma("unroll")                                                  \
                for (int reg = 0; reg < 4; ++reg) {                                \
                    const int row_ = (m << 4) + (kg << 2) + reg;                   \
                    const float v_ = fmaxf(acc[m][j][reg] + bball[lbb_ + j], 0.f); \
                    const int swc_ = (w << 3) + (((j << 1) + (lr >> 3)) ^ (row_ & 7)); \
                    ls[(row_ << 9) + (swc_ << 3) + (lr & 7)] = f2bf(v_);           \
                }                                                                  \
                acc[m][j] = f32x4{0.f, 0.f, 0.f, 0.f};                             \
            }                                                                      \
        asm volatile("s_waitcnt lgkmcnt(0)" ::: "memory");                         \
        __builtin_amdgcn_s_barrier();                                              \
        READA(afN, (s_) + 1);                                                      \
    }                                                                              \
    b1 = b2; b2 = (b2 + 1 == 3) ? 0 : b2 + 1;                                      \
} while (0)

    int b1 = 1, b2 = 2;
    for (int sp = 0; sp < 32; ++sp) {
        const int s0 = sp << 1;
        ITER(s0,     afA, bvA, afB, bvB);
        ITER(s0 + 1, afB, bvB, afA, bvA);
    }

    // ---- final epilogue (bball[12..15] = layer-3 bias) ----
    if (PHASE == 0) {
        __syncthreads();
#pragma unroll
        for (int m = 0; m < 4; ++m)
#pragma unroll
            for (int j = 0; j < 4; ++j)
#pragma unroll
                for (int reg = 0; reg < 4; ++reg) {
                    const int row = (m << 4) + (kg << 2) + reg;
                    const int col = (w << 6) + (j << 4) + lr;
                    const float h = fmaxf(acc[m][j][reg] + bball[12 + j], 0.f);
                    const float sv = sf32[(((size_t)((tile << 6) + row)) << 9) + col];
                    const int swc = (w << 3) + (((j << 1) + (lr >> 3)) ^ (row & 7));
                    const int idx = (row << 9) + (swc << 3) + (lr & 7);
                    ls[idx] = f2bf(sv - h);             // srel in A area
                    ls[32768 + idx] = f2bf(h);          // h in W area
                }
        __syncthreads();
#pragma unroll
        for (int c8 = 0; c8 < 8; ++c8) {
            const int row = (c8 << 3) + w;
            const size_t go = (((size_t)((tile << 6) + row)) << 9) + (asrc_c << 3);
            bf16x8 va = *reinterpret_cast<const bf16x8*>(&ls[(c8 << 12) + (t << 3)]);
            bf16x8 vh = *reinterpret_cast<const bf16x8*>(&ls[32768 + (c8 << 12) + (t << 3)]);
            *reinterpret_cast<bf16x8*>(&srel_out[go]) = va;
            *reinterpret_cast<bf16x8*>(&h_out[go]) = vh;
        }
    } else {
#pragma unroll
        for (int m = 0; m < 4; ++m) {
#pragma unroll
            for (int reg = 0; reg < 4; ++reg) {
                const int row = (m << 4) + (kg << 2) + reg;
                const int pr = perm[(tile << 6) + row];
                if (pr >= 0) {
#pragma unroll
                    for (int j = 0; j < 4; ++j) {
                        const int col = (w << 6) + (j << 4) + lr;
                        const size_t gi = (((size_t)pr) << 9) + col;
                        outf[gi] = acc[m][j][reg] + bball[12 + j] + bf2f(h_in[gi]);
                    }
                }
            }
        }
    }
#undef ITER
#undef STAGE
#undef READW
#undef READA
}

// ---------------- launch ----------------
extern "C" void kernel_launch(void* const* d_in, const int* in_sizes, int n_in,
                              void* d_out, int out_size, void* d_ws, size_t ws_size,
                              hipStream_t stream)
{
    const float* s     = (const float*)d_in[0];
    const int*   y     = (const int*)d_in[1];
    const float* dec_W = (const float*)d_in[2];
    const float* dec_b = (const float*)d_in[3];
    const float* exp_W = (const float*)d_in[4];
    const float* exp_b = (const float*)d_in[5];
    float* out = (float*)d_out;

    unsigned short* decWb = (unsigned short*)d_ws;              // 4*512*512 bf16 (2 MB)
    unsigned short* expWb = decWb + 4 * 512 * 512;              // 32*512*512 bf16 (16 MB)
    unsigned short* srel  = expWb + 8 * 4 * 512 * 512;          // BB*512 bf16 (16 MB)
    unsigned short* hbuf  = srel + (size_t)BB * 512;            // BB*512 bf16 (16 MB)
    int* perm     = (int*)(hbuf + (size_t)BB * 512);            // PR2
    int* counts   = perm + PR2;                                 // 8
    int* cursors  = counts + 8;                                 // 8
    int* starts   = cursors + 8;                                // 9
    int* tile_exp = starts + 9;                                 // MAXT2

    cvt_bf16<<<256, 256, 0, stream>>>(dec_W, decWb, (4 * 512 * 512) / 4);
    cvt_bf16<<<2048, 256, 0, stream>>>(exp_W, expWb, (8 * 4 * 512 * 512) / 4);

    bucket_init<<<(PR2 + 255) / 256, 256, 0, stream>>>(perm, counts, cursors, tile_exp);
    bucket_count<<<BB / 1024, 1024, 0, stream>>>(y, counts);
    bucket_scan<<<1, 64, 0, stream>>>(counts, starts, tile_exp);
    bucket_scatter<<<BB / 1024, 1024, 0, stream>>>(y, starts, cursors, perm);

    fused4<0><<<256, 512, 0, stream>>>(s, nullptr, decWb, dec_b, srel, hbuf,
                                       nullptr, nullptr, nullptr, nullptr, nullptr);
    fused4<1><<<MAXT2, 512, 0, stream>>>(nullptr, srel, expWb, exp_b, nullptr, nullptr,
                                         hbuf, out, perm, tile_exp, starts + 8);
}

// Round 11
// 164.688 us; speedup vs baseline: 1.5390x; 1.1013x over previous
//
#include <hip/hip_runtime.h>
#include <stdint.h>

#define BB 16384
#define PR2 16896     // 16384 + 8*64 worst-case bucket padding (64-granular)
#define MAXT2 264     // PR2/64 = 8*33

typedef short bf16x8 __attribute__((ext_vector_type(8)));
typedef float f32x4 __attribute__((ext_vector_type(4)));

typedef __attribute__((address_space(1))) unsigned short gus_t;
typedef __attribute__((address_space(3))) unsigned short lus_t;

__device__ __forceinline__ unsigned short f2bf(float f) {
    unsigned int u = __float_as_uint(f);
    u += 0x7fffu + ((u >> 16) & 1u);   // RNE
    return (unsigned short)(u >> 16);
}
__device__ __forceinline__ float bf2f(unsigned short h) {
    return __uint_as_float(((unsigned int)h) << 16);
}

__device__ __forceinline__ void gld16(const unsigned short* g, unsigned short* l) {
    __builtin_amdgcn_global_load_lds(
        reinterpret_cast<const gus_t*>(reinterpret_cast<uintptr_t>(g)),
        reinterpret_cast<lus_t*>(reinterpret_cast<uintptr_t>(l)),
        16, 0, 0);
}

// direct global->VGPR 16B load via asm: stays where issued (volatile ordering),
// completion enforced by explicit counted s_waitcnt vmcnt(N) + sched_barrier (rule #18)
#define GLOAD(dst_, ptr_) \
    asm volatile("global_load_dwordx4 %0, %1, off" : "=v"(dst_) : "v"(ptr_) : "memory")

// ---------------- transposing weight conversion ----------------
// Wt[li][ks][col][kg] (16B granules) <- W[li][col][ks*32+kg*8 .. +8]  (f32 -> bf16)
// li 0..3 = decomposer layers, 4..35 = expert e layers (e*4+l).
// A wave's MFMA B-fragment load becomes 64 lanes x 16B CONTIGUOUS (16 lines).
__global__ __launch_bounds__(256) void cvt_wt(const float* __restrict__ dec_W,
                                              const float* __restrict__ exp_W,
                                              unsigned short* __restrict__ dst) {
    const int g = blockIdx.x * 256 + threadIdx.x;   // 36*32768 granules exactly
    const int li = g >> 15;
    const int r = g & 32767;
    const int col = r >> 6;
    const int ks = (r >> 2) & 15;
    const int kg = r & 3;
    const float* src = (li < 4 ? dec_W + ((size_t)li << 18)
                               : exp_W + ((size_t)(li - 4) << 18))
                     + (col << 9) + (ks << 5) + (kg << 3);
    f32x4 v0 = *reinterpret_cast<const f32x4*>(src);
    f32x4 v1 = *reinterpret_cast<const f32x4*>(src + 4);
    bf16x8 o;
#pragma unroll
    for (int q = 0; q < 4; ++q) { o[q] = (short)f2bf(v0[q]); o[q + 4] = (short)f2bf(v1[q]); }
    *reinterpret_cast<bf16x8*>(dst + ((size_t)li << 18) + (ks << 14) + (col << 5) + (kg << 3)) = o;
}

// ---------------- bucketing (64-granular, block-aggregated atomics) ----------------
__global__ void bucket_init(int* perm, int* counts, int* cursors, int* tile_exp) {
    int i = blockIdx.x * blockDim.x + threadIdx.x;
    if (i < PR2) perm[i] = -1;
    if (i < 8) { counts[i] = 0; cursors[i] = 0; }
    if (i < MAXT2) tile_exp[i] = 0;
}

__global__ __launch_bounds__(1024) void bucket_count(const int* __restrict__ y, int* counts) {
    __shared__ int lc[8];
    const int t = threadIdx.x;
    if (t < 8) lc[t] = 0;
    __syncthreads();
    atomicAdd(&lc[y[blockIdx.x * 1024 + t]], 1);
    __syncthreads();
    if (t < 8) atomicAdd(&counts[t], lc[t]);
}

__global__ void bucket_scan(const int* __restrict__ counts, int* starts, int* tile_exp) {
    if (threadIdx.x == 0 && blockIdx.x == 0) {
        int s = 0;
        for (int e = 0; e < 8; ++e) {
            starts[e] = s;
            int nt = (counts[e] + 63) >> 6;
            for (int t = 0; t < nt; ++t) tile_exp[(s >> 6) + t] = e;
            s += nt << 6;
        }
        starts[8] = s;
    }
}

__global__ __launch_bounds__(1024) void bucket_scatter(const int* __restrict__ y,
                                                       const int* __restrict__ starts,
                                                       int* cursors, int* perm) {
    __shared__ int lc[8];
    __shared__ int lbase[8];
    const int t = threadIdx.x;
    if (t < 8) lc[t] = 0;
    __syncthreads();
    const int i = blockIdx.x * 1024 + t;
    const int e = y[i];
    const int r = atomicAdd(&lc[e], 1);
    __syncthreads();
    if (t < 8) lbase[t] = atomicAdd(&cursors[t], lc[t]);
    __syncthreads();
    perm[starts[e] + lbase[e] + r] = i;
}

// ---------------- fused 4-layer MLP: A in LDS (64 KB), W global->VGPR ----------------
// 1024 threads / 16 waves, wave w owns 64 rows x cols [w*32, w*32+32). acc[4][2].
// No W-LDS, no DMA, no per-step barriers (only 3 layer boundaries + epilogue).
// W loaded per-iter via 2 asm GLOADs (2-set rotation, ~1.7-iter flight, vmcnt(2)).
// A-LDS layout (verified R5-R10): chunk c of row r at slot (c&56)|((c^r)&7).
#define MFMA8(afX, bvX)                                                              \
    acc[0][0] = __builtin_amdgcn_mfma_f32_16x16x32_bf16(afX##0, bvX[0], acc[0][0], 0, 0, 0); \
    acc[0][1] = __builtin_amdgcn_mfma_f32_16x16x32_bf16(afX##0, bvX[1], acc[0][1], 0, 0, 0); \
    acc[1][0] = __builtin_amdgcn_mfma_f32_16x16x32_bf16(afX##1, bvX[0], acc[1][0], 0, 0, 0); \
    acc[1][1] = __builtin_amdgcn_mfma_f32_16x16x32_bf16(afX##1, bvX[1], acc[1][1], 0, 0, 0); \
    acc[2][0] = __builtin_amdgcn_mfma_f32_16x16x32_bf16(afX##2, bvX[0], acc[2][0], 0, 0, 0); \
    acc[2][1] = __builtin_amdgcn_mfma_f32_16x16x32_bf16(afX##2, bvX[1], acc[2][1], 0, 0, 0); \
    acc[3][0] = __builtin_amdgcn_mfma_f32_16x16x32_bf16(afX##3, bvX[0], acc[3][0], 0, 0, 0); \
    acc[3][1] = __builtin_amdgcn_mfma_f32_16x16x32_bf16(afX##3, bvX[1], acc[3][1], 0, 0, 0);

template <int PHASE>
__global__ __launch_bounds__(1024) void fused4(
    const float* __restrict__ sf32,
    const unsigned short* __restrict__ srelg,
    const unsigned short* __restrict__ Wb,      // transposed layout base
    const float* __restrict__ biasb,
    unsigned short* __restrict__ srel_out,
    unsigned short* __restrict__ h_out,
    const unsigned short* __restrict__ h_in,
    float* __restrict__ outf,
    const int* __restrict__ perm,
    const int* __restrict__ tile_exp,
    const int* __restrict__ starts8)
{
    __shared__ __align__(16) unsigned short ls[32768];   // 64 KB: A tile only

    const int bid = blockIdx.x;
    int tile;
    if (PHASE == 0) {
        tile = ((bid & 7) << 5) + (bid >> 3);             // XCD swizzle, 256 = 8*32
    } else {
        tile = (bid & 7) * 33 + (bid >> 3);               // XCD swizzle, 264 = 8*33
        if ((tile << 6) >= starts8[0]) return;
    }

    const unsigned short* Wl;
    const float* bl;
    if (PHASE == 0) { Wl = Wb; bl = biasb; }
    else {
        const int e = tile_exp[tile];
        Wl = Wb + ((size_t)e << 20);                      // e*4*262144 elems
        bl = biasb + (e << 11);
    }

    const int t = threadIdx.x;
    const int w = t >> 6;                                 // 0..15
    const int lane = t & 63;
    const int lr = lane & 15;
    const int kg = lane >> 4;
    const int off = ((tile * 3) + w) & 15;                // per-wave K-stagger

    const int ac = (t & 56) | ((t ^ w) & 7);              // A stage src chunk (inv-swizzle)
    const int axor = lr & 7;
    const int arow0 = ((0 << 4) + lr) << 9;
    const int arow1 = ((1 << 4) + lr) << 9;
    const int arow2 = ((2 << 4) + lr) << 9;
    const int arow3 = ((3 << 4) + lr) << 9;

    // per-lane W fragment base (transposed layout): col*32 + kg*8 elems
    const unsigned short* wpt0 = Wl + ((((w << 5) + lr)) << 5) + (kg << 3);
    const unsigned short* wpt1 = wpt0 + 512;              // col + 16

    // ---- biases for all 4 layers (2 cols/wave-thread) ----
    float bball[8];
#pragma unroll
    for (int l = 0; l < 4; ++l) {
        bball[(l << 1) + 0] = bl[(l << 9) + (w << 5) + lr];
        bball[(l << 1) + 1] = bl[(l << 9) + (w << 5) + 16 + lr];
    }

    // ---- initial A stage ----
    if (PHASE == 0) {
#pragma unroll
        for (int c4 = 0; c4 < 4; ++c4) {
            const int grow = (tile << 6) + (c4 << 4) + w;
            const float* sp = sf32 + (((size_t)grow) << 9) + (ac << 3);
            f32x4 v0 = *reinterpret_cast<const f32x4*>(sp);
            f32x4 v1 = *reinterpret_cast<const f32x4*>(sp + 4);
            bf16x8 o;
#pragma unroll
            for (int q = 0; q < 4; ++q) { o[q] = (short)f2bf(v0[q]); o[q + 4] = (short)f2bf(v1[q]); }
            *reinterpret_cast<bf16x8*>(&ls[(c4 << 13) + (t << 3)]) = o;
        }
    } else {
#pragma unroll
        for (int c4 = 0; c4 < 4; ++c4) {
            int pr = perm[(tile << 6) + (c4 << 4) + w];
            if (pr < 0) pr = 0;
            gld16(srelg + (((size_t)pr) << 9) + (ac << 3), ls + (c4 << 13) + (t << 3));
        }
    }

    // ---- W register prologue: sets for steps 0 and 1 ----
    bf16x8 bv0[2], bv1[2];
    {
        const size_t l0 = ((size_t)(off & 15)) << 14;
        const size_t l1 = ((size_t)((1 + off) & 15)) << 14;
        GLOAD(bv0[0], wpt0 + l0); GLOAD(bv0[1], wpt1 + l0);
        GLOAD(bv1[0], wpt0 + l1); GLOAD(bv1[1], wpt1 + l1);
    }
    if (PHASE == 0) {
        asm volatile("s_waitcnt lgkmcnt(0)" ::: "memory");   // my A ds_writes done
    } else {
        asm volatile("s_waitcnt vmcnt(4)" ::: "memory");     // A DMA done (W still in flight)
    }
    __builtin_amdgcn_s_barrier();                            // A visible to all waves

    f32x4 acc[4][2];
#pragma unroll
    for (int m = 0; m < 4; ++m) { acc[m][0] = f32x4{0,0,0,0}; acc[m][1] = f32x4{0,0,0,0}; }

#define ITER(s_, bvS) do {                                                         \
    if ((s_) < 62) asm volatile("s_waitcnt vmcnt(2)" ::: "memory");                \
    else           asm volatile("s_waitcnt vmcnt(0)" ::: "memory");                \
    __builtin_amdgcn_sched_barrier(0);                                             \
    {                                                                              \
        const int st_ = (((s_) & 15) + off) & 15;                                  \
        const int sb_ = (st_ >> 1) << 6;                                           \
        const int klo_ = ((((st_ & 1) << 2) | kg) ^ axor) << 3;                    \
        bf16x8 af_0 = *reinterpret_cast<const bf16x8*>(&ls[arow0 + sb_ + klo_]);   \
        bf16x8 af_1 = *reinterpret_cast<const bf16x8*>(&ls[arow1 + sb_ + klo_]);   \
        bf16x8 af_2 = *reinterpret_cast<const bf16x8*>(&ls[arow2 + sb_ + klo_]);   \
        bf16x8 af_3 = *reinterpret_cast<const bf16x8*>(&ls[arow3 + sb_ + klo_]);   \
        MFMA8(af_, bvS)                                                            \
    }                                                                              \
    if ((s_) + 2 < 64) {                                                           \
        const size_t lofs_ = (((size_t)(((s_) + 2) >> 4)) << 18)                   \
                           + (((size_t)(((((s_) + 2) & 15) + off) & 15)) << 14);   \
        GLOAD(bvS[0], wpt0 + lofs_);                                               \
        GLOAD(bvS[1], wpt1 + lofs_);                                               \
    }                                                                              \
    if (((s_) & 15) == 15 && (s_) < 63) {                                          \
        __builtin_amdgcn_s_barrier();        /* all waves done reading A */        \
        const int lb_ = ((s_) >> 4) << 1;                                          \
        _Pragma("unroll")                                                          \
        for (int m = 0; m < 4; ++m)                                                \
            _Pragma("unroll")                                                      \
            for (int j = 0; j < 2; ++j) {                                          \
                _Pragma("unroll")                                                  \
                for (int reg = 0; reg < 4; ++reg) {                                \
                    const int row_ = (m << 4) + (kg << 2) + reg;                   \
                    const float v_ = fmaxf(acc[m][j][reg] + bball[lb_ + j], 0.f);  \
                    const int c_ = (w << 2) + (j << 1) + (lr >> 3);                \
                    const int slot_ = (c_ & 56) | ((c_ ^ row_) & 7);               \
                    ls[(row_ << 9) + (slot_ << 3) + (lr & 7)] = f2bf(v_);          \
                }                                                                  \
                acc[m][j] = f32x4{0, 0, 0, 0};                                     \
            }                                                                      \
        asm volatile("s_waitcnt lgkmcnt(0)" ::: "memory");                         \
        __builtin_amdgcn_s_barrier();                                              \
    }                                                                              \
} while (0)

    for (int sp = 0; sp < 32; ++sp) {
        const int s0 = sp << 1;
        ITER(s0, bv0);
        ITER(s0 + 1, bv1);
    }
#undef ITER

    // ---- final epilogue (bball[6..7] = layer-3 bias) ----
    if (PHASE == 0) {
        __syncthreads();   // all waves done reading A
        // pass 1: srel = s - h
#pragma unroll
        for (int m = 0; m < 4; ++m)
#pragma unroll
            for (int j = 0; j < 2; ++j)
#pragma unroll
                for (int reg = 0; reg < 4; ++reg) {
                    const int row = (m << 4) + (kg << 2) + reg;
                    const int col = (w << 5) + (j << 4) + lr;
                    const float h = fmaxf(acc[m][j][reg] + bball[6 + j], 0.f);
                    const float sv = sf32[(((size_t)((tile << 6) + row)) << 9) + col];
                    const int c = (w << 2) + (j << 1) + (lr >> 3);
                    const int slot = (c & 56) | ((c ^ row) & 7);
                    ls[(row << 9) + (slot << 3) + (lr & 7)] = f2bf(sv - h);
                }
        __syncthreads();
#pragma unroll
        for (int c4 = 0; c4 < 4; ++c4) {
            const int row = (c4 << 4) + w;
            const size_t go = (((size_t)((tile << 6) + row)) << 9) + (ac << 3);
            *reinterpret_cast<bf16x8*>(&srel_out[go]) =
                *reinterpret_cast<const bf16x8*>(&ls[(c4 << 13) + (t << 3)]);
        }
        __syncthreads();
        // pass 2: h (acc still live)
#pragma unroll
        for (int m = 0; m < 4; ++m)
#pragma unroll
            for (int j = 0; j < 2; ++j)
#pragma unroll
                for (int reg = 0; reg < 4; ++reg) {
                    const int row = (m << 4) + (kg << 2) + reg;
                    const float h = fmaxf(acc[m][j][reg] + bball[6 + j], 0.f);
                    const int c = (w << 2) + (j << 1) + (lr >> 3);
                    const int slot = (c & 56) | ((c ^ row) & 7);
                    ls[(row << 9) + (slot << 3) + (lr & 7)] = f2bf(h);
                }
        __syncthreads();
#pragma unroll
        for (int c4 = 0; c4 < 4; ++c4) {
            const int row = (c4 << 4) + w;
            const size_t go = (((size_t)((tile << 6) + row)) << 9) + (ac << 3);
            *reinterpret_cast<bf16x8*>(&h_out[go]) =
                *reinterpret_cast<const bf16x8*>(&ls[(c4 << 13) + (t << 3)]);
        }
    } else {
#pragma unroll
        for (int m = 0; m < 4; ++m) {
#pragma unroll
            for (int reg = 0; reg < 4; ++reg) {
                const int row = (m << 4) + (kg << 2) + reg;
                const int pr = perm[(tile << 6) + row];
                if (pr >= 0) {
#pragma unroll
                    for (int j = 0; j < 2; ++j) {
                        const int col = (w << 5) + (j << 4) + lr;
                        const size_t gi = (((size_t)pr) << 9) + col;
                        outf[gi] = acc[m][j][reg] + bball[6 + j] + bf2f(h_in[gi]);
                    }
                }
            }
        }
    }
}

// ---------------- launch ----------------
extern "C" void kernel_launch(void* const* d_in, const int* in_sizes, int n_in,
                              void* d_out, int out_size, void* d_ws, size_t ws_size,
                              hipStream_t stream)
{
    const float* s     = (const float*)d_in[0];
    const int*   y     = (const int*)d_in[1];
    const float* dec_W = (const float*)d_in[2];
    const float* dec_b = (const float*)d_in[3];
    const float* exp_W = (const float*)d_in[4];
    const float* exp_b = (const float*)d_in[5];
    float* out = (float*)d_out;

    unsigned short* Wt   = (unsigned short*)d_ws;               // 36*262144 bf16 (18.9 MB), transposed
    unsigned short* srel = Wt + (size_t)36 * 262144;            // BB*512 bf16 (16 MB)
    unsigned short* hbuf = srel + (size_t)BB * 512;             // BB*512 bf16 (16 MB)
    int* perm     = (int*)(hbuf + (size_t)BB * 512);            // PR2
    int* counts   = perm + PR2;                                 // 8
    int* cursors  = counts + 8;                                 // 8
    int* starts   = cursors + 8;                                // 9
    int* tile_exp = starts + 9;                                 // MAXT2

    cvt_wt<<<4608, 256, 0, stream>>>(dec_W, exp_W, Wt);

    bucket_init<<<(PR2 + 255) / 256, 256, 0, stream>>>(perm, counts, cursors, tile_exp);
    bucket_count<<<BB / 1024, 1024, 0, stream>>>(y, counts);
    bucket_scan<<<1, 64, 0, stream>>>(counts, starts, tile_exp);
    bucket_scatter<<<BB / 1024, 1024, 0, stream>>>(y, starts, cursors, perm);

    fused4<0><<<256, 1024, 0, stream>>>(s, nullptr, Wt, dec_b, srel, hbuf,
                                        nullptr, nullptr, nullptr, nullptr, nullptr);
    fused4<1><<<MAXT2, 1024, 0, stream>>>(nullptr, srel, Wt + ((size_t)4 << 18), exp_b,
                                          nullptr, nullptr, hbuf, out,
                                          perm, tile_exp, starts + 8);
}